// Round 1
// baseline (268.089 us; speedup 1.0000x reference)
//
#include <hip/hip_runtime.h>
#include <math.h>

#define D_MODEL 128
#define N_STATE 64
#define SEQ_L   4096
#define CHUNK   8
#define GRID    (SEQ_L / CHUNK)   // 512 blocks = 2 per CU

typedef __attribute__((ext_vector_type(8))) __bf16 bf16x8;
typedef __attribute__((ext_vector_type(4))) float  f32x4;

// K[i] = (C . a^i) @ B, A diagonal. Computed TRANSPOSED via MFMA operand swap:
//   D_tile = (B^T-frag as A-op) x (Cs^T-frag as B-op)  ==> D[m][n] = K[n'][m']
// mfma_f32_16x16x32_bf16 layouts (verified pass in prior session):
//   A-op: A[m=lane&15][k=8*quad+j], B-op: B[k=8*quad+j][n=lane&15]
//   C/D : row m=4*quad+reg, col n=lane&15
//
// NEW this round: MFMA fragments are scattered (16B/lane at 512B row stride,
// 16 lines touched per store instr -> ~2.5x under write roofline). Stage each
// K-matrix through a 64 KiB LDS image with an XOR swizzle (idx16 ^= row&7,
// optimal 8-phase conflict-free both directions), then stream it out with
// wave-contiguous 1 KiB dwordx4 stores — same shape as the 6.7 TB/s fill.
__global__ __launch_bounds__(256, 2) void s4d_mfma_kernel(
    const float* __restrict__ A,   // 64x64 diagonal
    const float* __restrict__ B,   // 64x128
    const float* __restrict__ C,   // 128x64
    float* __restrict__ K)         // L x 128 x 128
{
    __shared__ float4 smem[4096];  // 64 KiB: one 128x128 f32 K-matrix

    const int tid  = threadIdx.x;
    const int w    = tid >> 6;     // wave 0..3: owns K-rows [32w, 32w+32)
    const int lane = tid & 63;
    const int ln   = lane & 15;
    const int q    = lane >> 4;
    const int i0   = blockIdx.x * CHUNK;

    // avec[s][j] = a_k, Csval[t][s][j] = C[d][k] * a_k^i0   (k = 32s+8q+j,
    // d = 32w+16t+ln).  Scaled C is carried forward: Csval *= avec per step.
    float avec[2][8], Csval[2][2][8];
    #pragma unroll
    for (int s = 0; s < 2; ++s)
        #pragma unroll
        for (int j = 0; j < 8; ++j) {
            const int k = 32*s + 8*q + j;
            const float a = A[k * N_STATE + k];
            avec[s][j] = a;
            const float p = powf(a, (float)i0);   // powf(0,0)=1 handles i0=0
            #pragma unroll
            for (int t = 0; t < 2; ++t)
                Csval[t][s][j] = C[(32*w + 16*t + ln) * N_STATE + k] * p;
        }

    // A-operand frags of the transposed GEMM = B matrix: B[32s+8q+j][16c+ln]
    bf16x8 Bfrag[8][2];
    #pragma unroll
    for (int c = 0; c < 8; ++c)
        #pragma unroll
        for (int s = 0; s < 2; ++s) {
            bf16x8 f;
            #pragma unroll
            for (int j = 0; j < 8; ++j)
                f[j] = (__bf16)B[(32*s + 8*q + j) * D_MODEL + 16*c + ln];
            Bfrag[c][s] = f;
        }

    float* out = K + (size_t)i0 * (D_MODEL * D_MODEL);

    // Read-phase swizzled 16B-index: lin16 = j*256 + tid, row = lin16>>5,
    // phys16 = lin16 ^ (row&7) = j*256 + (tid ^ (tid>>5)).
    const int rbase = tid ^ (tid >> 5);

    for (int i = 0; i < CHUNK; ++i) {
        // current scaled C -> bf16 B-operand frags
        bf16x8 Cfrag[2][2];
        #pragma unroll
        for (int t = 0; t < 2; ++t)
            #pragma unroll
            for (int s = 0; s < 2; ++s) {
                bf16x8 f;
                #pragma unroll
                for (int j = 0; j < 8; ++j)
                    f[j] = (__bf16)Csval[t][s][j];
                Cfrag[t][s] = f;
            }

        // advance scaled C by one power of the diagonal (independent of MFMA)
        #pragma unroll
        for (int t = 0; t < 2; ++t)
            #pragma unroll
            for (int s = 0; s < 2; ++s)
                #pragma unroll
                for (int j = 0; j < 8; ++j)
                    Csval[t][s][j] *= avec[s][j];

        // accumulate ALL 16 tiles (64 acc VGPRs)
        f32x4 acc[2][8];
        #pragma unroll
        for (int t = 0; t < 2; ++t)
            #pragma unroll
            for (int c = 0; c < 8; ++c) {
                f32x4 z = {0.f, 0.f, 0.f, 0.f};
                f32x4 d = __builtin_amdgcn_mfma_f32_16x16x32_bf16(
                    Bfrag[c][0], Cfrag[t][0], z, 0, 0, 0);
                d = __builtin_amdgcn_mfma_f32_16x16x32_bf16(
                    Bfrag[c][1], Cfrag[t][1], d, 0, 0, 0);
                acc[t][c] = d;   // = K[32w+16t+ln][16c+4q .. +3]
            }

        // stage to LDS, swizzled: off16 = r*32 + 4c + q, phys16 = off16 ^ (r&7)
        // (r&7 == ln&7). Per ds_write_b128 instr: 8 lanes per 16B bank-slot
        // = optimal 8 phases, conflict-free.
        #pragma unroll
        for (int t = 0; t < 2; ++t) {
            const int row16 = (32*w + 16*t + ln) * 32;
            const int swz   = ln & 7;
            #pragma unroll
            for (int c = 0; c < 8; ++c) {
                const int idx = (row16 + 4*c + q) ^ swz;
                smem[idx] = make_float4(acc[t][c][0], acc[t][c][1],
                                        acc[t][c][2], acc[t][c][3]);
            }
        }
        __syncthreads();

        // coalesced streaming stores: each wave writes contiguous 1 KiB
        #pragma unroll
        for (int j = 0; j < 16; ++j) {
            const float4 v = smem[j*256 + rbase];
            *(float4*)(out + j*1024 + tid*4) = v;
        }
        __syncthreads();   // smem reuse fence for next step's ds_writes

        out += D_MODEL * D_MODEL;
    }
}

extern "C" void kernel_launch(void* const* d_in, const int* in_sizes, int n_in,
                              void* d_out, int out_size, void* d_ws, size_t ws_size,
                              hipStream_t stream) {
    const float* A = (const float*)d_in[0];
    const float* B = (const float*)d_in[1];
    const float* C = (const float*)d_in[2];
    float* K = (float*)d_out;
    s4d_mfma_kernel<<<dim3(GRID), dim3(256), 0, stream>>>(A, B, C, K);
}